// Round 1
// baseline (953.018 us; speedup 1.0000x reference)
//
#include <hip/hip_runtime.h>

// VectorQuantizer: z [8192,1024] f32, embed [4096,256] f32
// outputs (flat f32): quantized_st [8388608], indices [32768], loss, codebook_loss, commitment_loss, perplexity

constexpr int D_CODE  = 256;
constexpr int M_ROWS  = 32768;       // 8192*4
constexpr int K_EMB   = 4096;
constexpr long Q_ELEMS = 8388608L;   // 8192*1024

// workspace layout (bytes)
constexpr size_t OFF_SUMZ = 0;         // 32768 f32  (128 KB)
constexpr size_t OFF_SUME = 131072;    // 4096 f32   (16 KB)
constexpr size_t OFF_PART = 147456;    // 4*32768 u64 (1 MB)
constexpr size_t OFF_IDX  = 1196032;   // 32768 i32  (128 KB)
constexpr size_t OFF_HIST = 1327104;   // 4096 u32   (16 KB)
constexpr size_t OFF_DACC = 1343488;   // 1 double
constexpr size_t ZERO_LEN = 16392;     // hist + dacc

__device__ __forceinline__ float comp4(const float4& v, int kr) {
  return kr == 0 ? v.x : (kr == 1 ? v.y : (kr == 2 ? v.z : v.w));
}
__device__ __forceinline__ unsigned long long umin64(unsigned long long a, unsigned long long b) {
  return a < b ? a : b;
}

// ---------------- kernel 1: row sums of squares (z and embed) ----------------
__global__ __launch_bounds__(256) void k_rowsums(const float* __restrict__ z,
                                                 const float* __restrict__ emb,
                                                 float* __restrict__ sumz,
                                                 float* __restrict__ sume) {
  int w = threadIdx.x >> 6, lane = threadIdx.x & 63;
  int row = blockIdx.x * 4 + w;                  // 0..36863
  const float* src;
  float* dst;
  if (row < M_ROWS) { src = z + (size_t)row * D_CODE; dst = sumz + row; }
  else              { src = emb + (size_t)(row - M_ROWS) * D_CODE; dst = sume + (row - M_ROWS); }
  float4 v = *(const float4*)(src + lane * 4);
  // any summation order is fine: argmin is invariant to grid shifts (binade-commuting rounding)
  float s = (v.x * v.x + v.y * v.y) + (v.z * v.z + v.w * v.w);
  #pragma unroll
  for (int off = 32; off; off >>= 1) s += __shfl_xor(s, off, 64);
  if (lane == 0) *dst = s;
}

// ---------------- kernel 2: fused fp32 distance + argmin (partial over candidate quarters) ----------------
// block: 256 thr; tx = tid&7 (candidate lanes), ty = tid>>3 (row groups).
// rows/block = 256 (8 per thread), candidates/block = 1024 (quarter), tiles of 128 cands x 32 k.
// LDS e-tile layout [k][c] with 132-float row pitch (+4 pad) -> conflict-free b128 reads.

#define LOADT(ST, KK)                                                                       \
  _Pragma("unroll")                                                                         \
  for (int p = 0; p < 4; ++p) {                                                             \
    int g = 4 * tid + p;                                                                    \
    ST[p] = *(const float4*)(emb + (size_t)(c0 + (g >> 3)) * D_CODE + (KK) * 32 + (g & 7) * 4); \
  }

#define STORET(ST)                                                                          \
  _Pragma("unroll")                                                                         \
  for (int p = 0; p < 4; ++p) {                                                             \
    int g = 4 * tid + p;                                                                    \
    int cc = g >> 3, kq = g & 7;                                                            \
    float* wp = ebuf + (size_t)(4 * kq) * 132 + cc;                                         \
    wp[0 * 132] = ST[p].x;                                                                  \
    wp[1 * 132] = ST[p].y;                                                                  \
    wp[2 * 132] = ST[p].z;                                                                  \
    wp[3 * 132] = ST[p].w;                                                                  \
  }

#define COMPUTE(KK)                                                                         \
  _Pragma("unroll 1")                                                                       \
  for (int kq = 0; kq < 8; ++kq) {                                                          \
    float4 zf[8];                                                                           \
    _Pragma("unroll")                                                                       \
    for (int i = 0; i < 8; ++i)                                                             \
      zf[i] = *(const float4*)(zb + (size_t)i * D_CODE + (KK) * 32 + kq * 4);               \
    const float* ebase = ebuf + (size_t)(4 * kq) * 132 + tx * 4;                            \
    _Pragma("unroll")                                                                       \
    for (int kr = 0; kr < 4; ++kr) {                                                        \
      _Pragma("unroll")                                                                     \
      for (int g4 = 0; g4 < 4; ++g4) {                                                      \
        float4 ef = *(const float4*)(ebase + kr * 132 + g4 * 32);                           \
        _Pragma("unroll")                                                                   \
        for (int i = 0; i < 8; ++i) {                                                       \
          float zs = comp4(zf[i], kr);                                                      \
          acc[i][4 * g4 + 0] = fmaf(zs, ef.x, acc[i][4 * g4 + 0]);                          \
          acc[i][4 * g4 + 1] = fmaf(zs, ef.y, acc[i][4 * g4 + 1]);                          \
          acc[i][4 * g4 + 2] = fmaf(zs, ef.z, acc[i][4 * g4 + 2]);                          \
          acc[i][4 * g4 + 3] = fmaf(zs, ef.w, acc[i][4 * g4 + 3]);                          \
        }                                                                                   \
      }                                                                                     \
    }                                                                                       \
  }

__global__ __launch_bounds__(256, 2) void k_argmin(const float* __restrict__ z,
                                                   const float* __restrict__ emb,
                                                   const float* __restrict__ sumz,
                                                   const float* __restrict__ sume,
                                                   unsigned long long* __restrict__ partial) {
  __shared__ float ebuf[32 * 132];                 // 16.5 KB, [k][c] padded
  __shared__ unsigned long long red[256][8];       // 16 KB reduce scratch

  const int tid = threadIdx.x;
  const int tx = tid & 7;
  const int ty = tid >> 3;
  const int rt = blockIdx.x >> 2;
  const int q  = blockIdx.x & 3;
  const int row0 = rt * 256;
  const int c00 = q * 1024;

  const float* zb = z + (size_t)(row0 + ty * 8) * D_CODE;

  unsigned long long best[8];
  #pragma unroll
  for (int i = 0; i < 8; ++i) best[i] = ~0ULL;

  for (int et = 0; et < 8; ++et) {
    const int c0 = c00 + et * 128;
    float acc[8][16];
    #pragma unroll
    for (int i = 0; i < 8; ++i)
      #pragma unroll
      for (int j = 0; j < 16; ++j) acc[i][j] = 0.0f;

    float4 stA[4], stB[4];
    LOADT(stA, 0)

    #pragma unroll 1
    for (int kk2 = 0; kk2 < 4; ++kk2) {
      // even step kk = 2*kk2
      __syncthreads();                 // previous users of ebuf done
      STORET(stA)
      LOADT(stB, 2 * kk2 + 1)         // prefetch next slice (latency hides under compute)
      __syncthreads();                 // tile visible
      COMPUTE(2 * kk2)
      // odd step kk = 2*kk2+1
      __syncthreads();
      STORET(stB)
      if (kk2 < 3) { LOADT(stA, 2 * kk2 + 2) }
      __syncthreads();
      COMPUTE(2 * kk2 + 1)
    }

    // epilogue: literal fp32 distance d = (sumz - 2*dot) + sume, first-index tie-break via packed key
    #pragma unroll
    for (int g4 = 0; g4 < 4; ++g4) {
      #pragma unroll
      for (int l = 0; l < 4; ++l) {
        int j = 4 * g4 + l;
        int cg = c0 + g4 * 32 + tx * 4 + l;
        float se = sume[cg];
        #pragma unroll
        for (int i = 0; i < 8; ++i) {
          float sz = sumz[row0 + ty * 8 + i];
          float dd = (sz - 2.0f * acc[i][j]) + se;   // same roundings as the reference
          unsigned long long key =
              ((unsigned long long)__float_as_uint(dd) << 32) | (unsigned int)cg;
          best[i] = umin64(best[i], key);
        }
      }
    }
  }

  // cross-thread (tx) reduce per row
  #pragma unroll
  for (int i = 0; i < 8; ++i) red[ty * 8 + i][tx] = best[i];
  __syncthreads();
  {
    int r = tid;
    unsigned long long b = red[r][0];
    #pragma unroll
    for (int t = 1; t < 8; ++t) b = umin64(b, red[r][t]);
    partial[(size_t)q * M_ROWS + row0 + r] = b;
  }
}

// ---------------- kernel 3: merge partials, emit indices + histogram ----------------
__global__ __launch_bounds__(256) void k_merge(const unsigned long long* __restrict__ partial,
                                               int* __restrict__ idx,
                                               float* __restrict__ outI,
                                               unsigned int* __restrict__ hist) {
  int r = blockIdx.x * 256 + threadIdx.x;
  unsigned long long b = partial[r];
  b = umin64(b, partial[(size_t)M_ROWS + r]);
  b = umin64(b, partial[2 * (size_t)M_ROWS + r]);
  b = umin64(b, partial[3 * (size_t)M_ROWS + r]);
  int id = (int)(unsigned int)(b & 0xffffffffULL);
  idx[r] = id;
  outI[r] = (float)id;
  atomicAdd(&hist[id], 1u);
}

// ---------------- kernel 4: quantized_st (bit-exact) + commitment accumulator ----------------
__global__ __launch_bounds__(256) void k_quant(const float* __restrict__ z,
                                               const float* __restrict__ emb,
                                               const int* __restrict__ idx,
                                               float* __restrict__ outQ,
                                               double* __restrict__ dacc) {
  __shared__ double sd[256];
  const long NF4 = Q_ELEMS / 4;                    // 2097152 float4
  long f0 = (long)blockIdx.x * 256 + threadIdx.x;  // 524288 threads
  double s = 0.0;
  for (long f = f0; f < NF4; f += 524288) {
    long m = f >> 6;                               // flat_z row
    int d4 = (int)(f & 63) * 4;
    int id = idx[m];
    float4 zv = *(const float4*)(z + f * 4);
    float4 qv = *(const float4*)(emb + (size_t)id * D_CODE + d4);
    float dx = qv.x - zv.x, dy = qv.y - zv.y, dz = qv.z - zv.z, dw = qv.w - zv.w;
    float4 ov;
    ov.x = zv.x + dx; ov.y = zv.y + dy; ov.z = zv.z + dz; ov.w = zv.w + dw;  // z + (q - z), literal
    *(float4*)(outQ + f * 4) = ov;
    s += (double)dx * (double)dx + (double)dy * (double)dy
       + (double)dz * (double)dz + (double)dw * (double)dw;
  }
  sd[threadIdx.x] = s;
  __syncthreads();
  #pragma unroll
  for (int o = 128; o; o >>= 1) {
    if (threadIdx.x < o) sd[threadIdx.x] += sd[threadIdx.x + o];
    __syncthreads();
  }
  if (threadIdx.x == 0) atomicAdd(dacc, sd[0]);
}

// ---------------- kernel 5: scalars (loss, codebook_loss, commitment, perplexity) ----------------
__global__ __launch_bounds__(256) void k_final(const unsigned int* __restrict__ hist,
                                               const double* __restrict__ dacc,
                                               float* __restrict__ outS) {
  __shared__ double sd[256];
  double s = 0.0;
  for (int c = threadIdx.x; c < K_EMB; c += 256) {
    double p = (double)hist[c] * (1.0 / 32768.0);
    s += p * log(p + 1e-10);
  }
  sd[threadIdx.x] = s;
  __syncthreads();
  #pragma unroll
  for (int o = 128; o; o >>= 1) {
    if (threadIdx.x < o) sd[threadIdx.x] += sd[threadIdx.x + o];
    __syncthreads();
  }
  if (threadIdx.x == 0) {
    float commit = (float)(dacc[0] / (double)Q_ELEMS);
    outS[0] = 0.25f * commit;   // loss = 1.0*0 + 0.25*commitment
    outS[1] = 0.0f;             // codebook_loss (EMA eval mode)
    outS[2] = commit;           // commitment_loss
    outS[3] = (float)exp(-sd[0]);  // perplexity
  }
}

extern "C" void kernel_launch(void* const* d_in, const int* in_sizes, int n_in,
                              void* d_out, int out_size, void* d_ws, size_t ws_size,
                              hipStream_t stream) {
  const float* z   = (const float*)d_in[0];
  const float* emb = (const float*)d_in[1];
  float* out = (float*)d_out;
  char* ws = (char*)d_ws;

  float* sumz = (float*)(ws + OFF_SUMZ);
  float* sume = (float*)(ws + OFF_SUME);
  unsigned long long* partial = (unsigned long long*)(ws + OFF_PART);
  int* idx = (int*)(ws + OFF_IDX);
  unsigned int* hist = (unsigned int*)(ws + OFF_HIST);
  double* dacc = (double*)(ws + OFF_DACC);

  hipMemsetAsync(ws + OFF_HIST, 0, ZERO_LEN, stream);   // hist + dacc

  k_rowsums<<<9216, 256, 0, stream>>>(z, emb, sumz, sume);
  k_argmin<<<512, 256, 0, stream>>>(z, emb, sumz, sume, partial);
  k_merge<<<M_ROWS / 256, 256, 0, stream>>>(partial, idx, out + Q_ELEMS, hist);
  k_quant<<<2048, 256, 0, stream>>>(z, emb, idx, out, dacc);
  k_final<<<1, 256, 0, stream>>>(hist, dacc, out + Q_ELEMS + M_ROWS);
}